// Round 2
// baseline (1222.352 us; speedup 1.0000x reference)
//
#include <hip/hip_runtime.h>
#include <math.h>

#define N_NODES 50000
#define N_EDGES 800000
#define EPS 1e-12f

// ---------------- K0: per-node precompute ----------------
__global__ void k_node_init(const float* __restrict__ X, const float* __restrict__ yp,
                            float4* __restrict__ px4, float* __restrict__ f) {
    int n = blockIdx.x * blockDim.x + threadIdx.x;
    if (n < N_NODES) {
        // x_in = [X[:,0], X[:,1], X[:,2], X[:,4], y_prev]
        px4[n] = make_float4(X[n * 6 + 0], X[n * 6 + 1], X[n * 6 + 2], X[n * 6 + 4]);
        f[n] = yp[n];
    }
}

// ---------------- K1: per-edge precompute ----------------
// NOTE: harness delivers int64 reference tensors as int32 on device.
__global__ void k_edge_init(const int* __restrict__ edge,
                            const float4* __restrict__ px4,
                            const float* __restrict__ yp,
                            int2* __restrict__ sd, float4* __restrict__ dnrm,
                            float4* __restrict__ ea, float* __restrict__ cnt) {
    int e = blockIdx.x * blockDim.x + threadIdx.x;
    if (e < N_EDGES) {
        int s = edge[e];
        int d = edge[N_EDGES + e];
        sd[e] = make_int2(s, d);
        float4 ps = px4[s], pd = px4[d];
        float dx = pd.x - ps.x, dy = pd.y - ps.y, dz = pd.z - ps.z;
        float nrm = sqrtf(dx * dx + dy * dy + dz * dz + EPS);
        dnrm[e] = make_float4(dx, dy, dz, nrm);
        float fr = yp[d] - yp[s];
        ea[e] = make_float4(fr * dx, fr * dy, fr * dz, 0.f);
        atomicAdd(&cnt[d], 1.0f);
    }
}

// ---------------- K2: edge MLP + scatter-add ----------------
// net_in[9] = {disp(3), norm, edge_attr(3), f_src, f_dst}; pad to 12.
__global__ __launch_bounds__(256) void k_edge_mlp(
    const int2* __restrict__ sd, const float4* __restrict__ dnrm,
    float4* __restrict__ ea, const float* __restrict__ f,
    const float* __restrict__ ew1, const float* __restrict__ eb1,
    const float* __restrict__ ew2, const float* __restrict__ eb2,
    const float* __restrict__ ew3, const float* __restrict__ eb3,
    float* __restrict__ aggr) {
    __shared__ float4 w1t[64 * 3];   // [j][i4], 12 inputs per j (padded from 9)
    __shared__ float4 w2t[64 * 16];  // [j][i4] transposed ew2
    __shared__ float4 w3b[64];       // {ew3[j][0..2], eb2[j]}
    __shared__ float  b1[64];
    __shared__ float  b3[4];
    int t = threadIdx.x;

    for (int idx = t; idx < 64 * 12; idx += 256) {
        int j = idx / 12, i = idx % 12;
        ((float*)w1t)[j * 12 + i] = (i < 9) ? ew1[i * 64 + j] : 0.f;
    }
    for (int idx = t; idx < 64 * 64; idx += 256) {
        int j = idx & 63, i = idx >> 6;  // idx = i*64+j (row-major ew2)
        ((float*)w2t)[j * 64 + i] = ew2[idx];
    }
    if (t < 64) {
        b1[t] = eb1[t];
        w3b[t] = make_float4(ew3[t * 3 + 0], ew3[t * 3 + 1], ew3[t * 3 + 2], eb2[t]);
    }
    if (t < 4) b3[t] = (t < 3) ? eb3[t] : 0.f;
    __syncthreads();

    int e = blockIdx.x * blockDim.x + t;
    if (e >= N_EDGES) return;

    int2 SD = sd[e];
    float4 DN = dnrm[e];
    float4 EA = ea[e];
    float fs = f[SD.x], fd = f[SD.y];

    float4 nin0 = DN;                                // disp.xyz, norm
    float4 nin1 = make_float4(EA.x, EA.y, EA.z, fs); // ea.xyz, f_src
    float4 nin2 = make_float4(fd, 0.f, 0.f, 0.f);    // f_dst, pad

    float h1[64];
#pragma unroll
    for (int j = 0; j < 64; j++) {
        float4 a = w1t[j * 3 + 0], b = w1t[j * 3 + 1], c = w1t[j * 3 + 2];
        float acc = b1[j];
        acc += a.x * nin0.x + a.y * nin0.y + a.z * nin0.z + a.w * nin0.w;
        acc += b.x * nin1.x + b.y * nin1.y + b.z * nin1.z + b.w * nin1.w;
        acc += c.x * nin2.x;
        h1[j] = fmaxf(acc, 0.f);
    }

    float o0 = b3[0], o1 = b3[1], o2 = b3[2];
#pragma unroll
    for (int j = 0; j < 64; j++) {
        float4 wb = w3b[j];
        float acc = wb.w;  // eb2[j]
#pragma unroll
        for (int i4 = 0; i4 < 16; i4++) {
            float4 w = w2t[j * 16 + i4];
            acc += w.x * h1[4 * i4 + 0] + w.y * h1[4 * i4 + 1] +
                   w.z * h1[4 * i4 + 2] + w.w * h1[4 * i4 + 3];
        }
        acc = fmaxf(acc, 0.f);
        o0 += acc * wb.x; o1 += acc * wb.y; o2 += acc * wb.z;
    }

    float r0 = EA.x + o0, r1 = EA.y + o1, r2 = EA.z + o2;
    ea[e] = make_float4(r0, r1, r2, 0.f);
    atomicAdd(&aggr[SD.y * 3 + 0], r0);
    atomicAdd(&aggr[SD.y * 3 + 1], r1);
    atomicAdd(&aggr[SD.y * 3 + 2], r2);
}

// ---------------- K3: node MLP, f += delta ----------------
// node_in[5] = {x3, f, aggr0, aggr1, aggr2}; pad to 8.
__global__ __launch_bounds__(256) void k_node_mlp(
    const float4* __restrict__ px4, float* __restrict__ f,
    const float* __restrict__ aggr, const float* __restrict__ cnt,
    const float* __restrict__ nw1, const float* __restrict__ nb1,
    const float* __restrict__ nw2, const float* __restrict__ nb2,
    const float* __restrict__ nw3, const float* __restrict__ nb3) {
    __shared__ __align__(16) float w1t[64 * 8];
    __shared__ __align__(16) float w2t[64 * 64];
    __shared__ float b1[64], b2[64], w3[64];
    int t = threadIdx.x;
    for (int idx = t; idx < 64 * 8; idx += 256) {
        int j = idx >> 3, i = idx & 7;
        w1t[idx] = (i < 5) ? nw1[i * 64 + j] : 0.f;
    }
    for (int idx = t; idx < 4096; idx += 256) {
        int j = idx & 63, i = idx >> 6;
        w2t[j * 64 + i] = nw2[idx];
    }
    if (t < 64) { b1[t] = nb1[t]; b2[t] = nb2[t]; w3[t] = nw3[t]; }
    __syncthreads();

    int n = blockIdx.x * blockDim.x + t;
    if (n >= N_NODES) return;

    float inv = 1.0f / fmaxf(cnt[n], 1.0f);
    float a0 = aggr[n * 3 + 0] * inv, a1 = aggr[n * 3 + 1] * inv, a2 = aggr[n * 3 + 2] * inv;
    float4 P = px4[n];
    float fn = f[n];
    float4 nin0 = make_float4(P.w, fn, a0, a1);
    float nin4 = a2;

    float h1[64];
#pragma unroll
    for (int j = 0; j < 64; j++) {
        const float4* r = (const float4*)&w1t[j * 8];
        float4 ra = r[0], rb = r[1];
        float acc = b1[j] + ra.x * nin0.x + ra.y * nin0.y + ra.z * nin0.z +
                    ra.w * nin0.w + rb.x * nin4;
        h1[j] = fmaxf(acc, 0.f);
    }

    float o = nb3[0];
#pragma unroll
    for (int j = 0; j < 64; j++) {
        const float4* r = (const float4*)&w2t[j * 64];
        float acc = b2[j];
#pragma unroll
        for (int i4 = 0; i4 < 16; i4++) {
            float4 w = r[i4];
            acc += w.x * h1[4 * i4 + 0] + w.y * h1[4 * i4 + 1] +
                   w.z * h1[4 * i4 + 2] + w.w * h1[4 * i4 + 3];
        }
        o += fmaxf(acc, 0.f) * w3[j];
    }
    f[n] = fn + o;
}

// ---------------- K4: decoder + residual ----------------
__global__ __launch_bounds__(256) void k_decoder(
    const float4* __restrict__ px4, const float* __restrict__ f,
    const float* __restrict__ yp,
    const float* __restrict__ dw1, const float* __restrict__ db1,
    const float* __restrict__ dw2, const float* __restrict__ db2,
    const float* __restrict__ dw3, const float* __restrict__ db3,
    const float* __restrict__ dw4, const float* __restrict__ db4,
    float* __restrict__ out) {
    __shared__ __align__(16) float w1t[64 * 8];
    __shared__ __align__(16) float w2t[64 * 64];
    __shared__ __align__(16) float w3t[64 * 64];
    __shared__ float b1[64], b2[64], b3[64], w4[64];
    int t = threadIdx.x;
    for (int idx = t; idx < 64 * 8; idx += 256) {
        int j = idx >> 3, i = idx & 7;
        w1t[idx] = (i < 5) ? dw1[i * 64 + j] : 0.f;
    }
    for (int idx = t; idx < 4096; idx += 256) {
        int j = idx & 63, i = idx >> 6;
        w2t[j * 64 + i] = dw2[idx];
        w3t[j * 64 + i] = dw3[idx];
    }
    if (t < 64) { b1[t] = db1[t]; b2[t] = db2[t]; b3[t] = db3[t]; w4[t] = dw4[t]; }
    __syncthreads();

    int n = blockIdx.x * blockDim.x + t;
    if (n >= N_NODES) return;

    float4 P = px4[n];
    float fn = f[n];
    float4 nin0 = make_float4(P.x, P.y, P.z, P.w);
    float nin4 = fn;

    float h1[64];
#pragma unroll
    for (int j = 0; j < 64; j++) {
        const float4* r = (const float4*)&w1t[j * 8];
        float4 ra = r[0], rb = r[1];
        float acc = b1[j] + ra.x * nin0.x + ra.y * nin0.y + ra.z * nin0.z +
                    ra.w * nin0.w + rb.x * nin4;
        h1[j] = fmaxf(acc, 0.f);
    }
    float h2[64];
#pragma unroll
    for (int j = 0; j < 64; j++) {
        const float4* r = (const float4*)&w2t[j * 64];
        float acc = b2[j];
#pragma unroll
        for (int i4 = 0; i4 < 16; i4++) {
            float4 w = r[i4];
            acc += w.x * h1[4 * i4 + 0] + w.y * h1[4 * i4 + 1] +
                   w.z * h1[4 * i4 + 2] + w.w * h1[4 * i4 + 3];
        }
        h2[j] = fmaxf(acc, 0.f);
    }
    float o = db4[0];
#pragma unroll
    for (int j = 0; j < 64; j++) {
        const float4* r = (const float4*)&w3t[j * 64];
        float acc = b3[j];
#pragma unroll
        for (int i4 = 0; i4 < 16; i4++) {
            float4 w = r[i4];
            acc += w.x * h2[4 * i4 + 0] + w.y * h2[4 * i4 + 1] +
                   w.z * h2[4 * i4 + 2] + w.w * h2[4 * i4 + 3];
        }
        o += fmaxf(acc, 0.f) * w4[j];
    }
    out[n] = yp[n] + o;
}

extern "C" void kernel_launch(void* const* d_in, const int* in_sizes, int n_in,
                              void* d_out, int out_size, void* d_ws, size_t ws_size,
                              hipStream_t stream) {
    const float* X    = (const float*)d_in[0];
    const float* yp   = (const float*)d_in[1];
    const int*   edge = (const int*)d_in[2];   // harness: integer -> const int*
    const float *ew1 = (const float*)d_in[3],  *eb1 = (const float*)d_in[4];
    const float *ew2 = (const float*)d_in[5],  *eb2 = (const float*)d_in[6];
    const float *ew3 = (const float*)d_in[7],  *eb3 = (const float*)d_in[8];
    const float *nw1 = (const float*)d_in[9],  *nb1 = (const float*)d_in[10];
    const float *nw2 = (const float*)d_in[11], *nb2 = (const float*)d_in[12];
    const float *nw3 = (const float*)d_in[13], *nb3 = (const float*)d_in[14];
    const float *dw1 = (const float*)d_in[15], *db1 = (const float*)d_in[16];
    const float *dw2 = (const float*)d_in[17], *db2 = (const float*)d_in[18];
    const float *dw3 = (const float*)d_in[19], *db3 = (const float*)d_in[20];
    const float *dw4 = (const float*)d_in[21], *db4 = (const float*)d_in[22];
    float* out = (float*)d_out;

    char* p = (char*)d_ws;
    auto carve = [&](size_t bytes) {
        char* r = p;
        p += (bytes + 255) & ~(size_t)255;
        return r;
    };
    int2*   sd   = (int2*)  carve(sizeof(int2)   * N_EDGES);
    float4* dnrm = (float4*)carve(sizeof(float4) * N_EDGES);
    float4* ea   = (float4*)carve(sizeof(float4) * N_EDGES);
    float4* px4  = (float4*)carve(sizeof(float4) * N_NODES);
    float*  f    = (float*) carve(sizeof(float)  * N_NODES);
    float*  cnt  = (float*) carve(sizeof(float)  * N_NODES);
    float*  aggr = (float*) carve(sizeof(float)  * 3 * N_NODES);

    const int nb_n = (N_NODES + 255) / 256;
    const int nb_e = (N_EDGES + 255) / 256;

    hipMemsetAsync(cnt, 0, sizeof(float) * N_NODES, stream);
    k_node_init<<<nb_n, 256, 0, stream>>>(X, yp, px4, f);
    k_edge_init<<<nb_e, 256, 0, stream>>>(edge, px4, yp, sd, dnrm, ea, cnt);

    for (int it = 0; it < 3; ++it) {
        hipMemsetAsync(aggr, 0, sizeof(float) * 3 * N_NODES, stream);
        k_edge_mlp<<<nb_e, 256, 0, stream>>>(sd, dnrm, ea, f,
                                             ew1, eb1, ew2, eb2, ew3, eb3, aggr);
        k_node_mlp<<<nb_n, 256, 0, stream>>>(px4, f, aggr, cnt,
                                             nw1, nb1, nw2, nb2, nw3, nb3);
    }
    k_decoder<<<nb_n, 256, 0, stream>>>(px4, f, yp,
                                        dw1, db1, dw2, db2, dw3, db3, dw4, db4, out);
}

// Round 3
// 847.541 us; speedup vs baseline: 1.4422x; 1.4422x over previous
//
#include <hip/hip_runtime.h>
#include <math.h>

#define N_NODES 50000
#define N_EDGES 800000
#define EPS 1e-12f

// ---------------- K0: per-node precompute ----------------
__global__ void k_node_init(const float* __restrict__ X, const float* __restrict__ yp,
                            float4* __restrict__ px4, float* __restrict__ f) {
    int n = blockIdx.x * blockDim.x + threadIdx.x;
    if (n < N_NODES) {
        // x_in = [X[:,0], X[:,1], X[:,2], X[:,4], y_prev]
        px4[n] = make_float4(X[n * 6 + 0], X[n * 6 + 1], X[n * 6 + 2], X[n * 6 + 4]);
        f[n] = yp[n];
    }
}

// ---------------- K1: per-edge precompute ----------------
// NOTE: harness delivers int64 reference tensors as int32 on device.
__global__ void k_edge_init(const int* __restrict__ edge,
                            const float4* __restrict__ px4,
                            const float* __restrict__ yp,
                            int2* __restrict__ sd, float4* __restrict__ dnrm,
                            float4* __restrict__ ea, float* __restrict__ cnt) {
    int e = blockIdx.x * blockDim.x + threadIdx.x;
    if (e < N_EDGES) {
        int s = edge[e];
        int d = edge[N_EDGES + e];
        sd[e] = make_int2(s, d);
        float4 ps = px4[s], pd = px4[d];
        float dx = pd.x - ps.x, dy = pd.y - ps.y, dz = pd.z - ps.z;
        float nrm = sqrtf(dx * dx + dy * dy + dz * dz + EPS);
        dnrm[e] = make_float4(dx, dy, dz, nrm);
        float fr = yp[d] - yp[s];
        ea[e] = make_float4(fr * dx, fr * dy, fr * dz, 0.f);
        atomicAdd(&cnt[d], 1.0f);
    }
}

// ---------------- K2: edge MLP + scatter-add ----------------
// Weights read DIRECTLY from global with wave-uniform addresses -> compiler
// scalarizes to s_load (SGPR operand on v_fma), zero LDS traffic.
// Streaming outer-product: h1[i] is computed then immediately consumed into
// the 64 h2 accumulators, so only h2[64] lives in registers.
__global__ __launch_bounds__(256) void k_edge_mlp(
    const int2* __restrict__ sd, const float4* __restrict__ dnrm,
    float4* __restrict__ ea, const float* __restrict__ f,
    const float* __restrict__ ew1, const float* __restrict__ eb1,
    const float* __restrict__ ew2, const float* __restrict__ eb2,
    const float* __restrict__ ew3, const float* __restrict__ eb3,
    float* __restrict__ aggr) {
    int e = blockIdx.x * blockDim.x + threadIdx.x;
    if (e >= N_EDGES) return;

    int2 SD = sd[e];
    float4 DN = dnrm[e];
    float4 EA = ea[e];
    float fs = f[SD.x], fd = f[SD.y];

    float in9[9] = {DN.x, DN.y, DN.z, DN.w, EA.x, EA.y, EA.z, fs, fd};

    float h2[64];
#pragma unroll
    for (int j = 0; j < 64; j++) h2[j] = eb2[j];

#pragma unroll 4
    for (int i = 0; i < 64; i++) {
        float a = eb1[i];
#pragma unroll
        for (int k = 0; k < 9; k++) a += ew1[k * 64 + i] * in9[k];
        a = fmaxf(a, 0.f);
#pragma unroll
        for (int j = 0; j < 64; j++) h2[j] += a * ew2[i * 64 + j];
    }

    float o0 = eb3[0], o1 = eb3[1], o2 = eb3[2];
#pragma unroll 8
    for (int j = 0; j < 64; j++) {
        float r = fmaxf(h2[j], 0.f);
        o0 += r * ew3[j * 3 + 0];
        o1 += r * ew3[j * 3 + 1];
        o2 += r * ew3[j * 3 + 2];
    }

    float r0 = EA.x + o0, r1 = EA.y + o1, r2 = EA.z + o2;
    ea[e] = make_float4(r0, r1, r2, 0.f);
    atomicAdd(&aggr[SD.y * 3 + 0], r0);
    atomicAdd(&aggr[SD.y * 3 + 1], r1);
    atomicAdd(&aggr[SD.y * 3 + 2], r2);
}

// ---------------- K3: node MLP, f += delta ----------------
__global__ __launch_bounds__(256) void k_node_mlp(
    const float4* __restrict__ px4, float* __restrict__ f,
    const float* __restrict__ aggr, const float* __restrict__ cnt,
    const float* __restrict__ nw1, const float* __restrict__ nb1,
    const float* __restrict__ nw2, const float* __restrict__ nb2,
    const float* __restrict__ nw3, const float* __restrict__ nb3) {
    int n = blockIdx.x * blockDim.x + threadIdx.x;
    if (n >= N_NODES) return;

    float inv = 1.0f / fmaxf(cnt[n], 1.0f);
    float4 P = px4[n];
    float fn = f[n];
    float in5[5] = {P.w, fn, aggr[n * 3 + 0] * inv, aggr[n * 3 + 1] * inv,
                    aggr[n * 3 + 2] * inv};

    float h2[64];
#pragma unroll
    for (int j = 0; j < 64; j++) h2[j] = nb2[j];

#pragma unroll 4
    for (int i = 0; i < 64; i++) {
        float a = nb1[i];
#pragma unroll
        for (int k = 0; k < 5; k++) a += nw1[k * 64 + i] * in5[k];
        a = fmaxf(a, 0.f);
#pragma unroll
        for (int j = 0; j < 64; j++) h2[j] += a * nw2[i * 64 + j];
    }

    float o = nb3[0];
#pragma unroll 8
    for (int j = 0; j < 64; j++) o += fmaxf(h2[j], 0.f) * nw3[j];
    f[n] = fn + o;
}

// ---------------- K4: decoder + residual ----------------
__global__ __launch_bounds__(256) void k_decoder(
    const float4* __restrict__ px4, const float* __restrict__ f,
    const float* __restrict__ yp,
    const float* __restrict__ dw1, const float* __restrict__ db1,
    const float* __restrict__ dw2, const float* __restrict__ db2,
    const float* __restrict__ dw3, const float* __restrict__ db3,
    const float* __restrict__ dw4, const float* __restrict__ db4,
    float* __restrict__ out) {
    int n = blockIdx.x * blockDim.x + threadIdx.x;
    if (n >= N_NODES) return;

    float4 P = px4[n];
    float fn = f[n];
    float in5[5] = {P.x, P.y, P.z, P.w, fn};

    float h2[64];
#pragma unroll
    for (int j = 0; j < 64; j++) h2[j] = db2[j];

#pragma unroll 4
    for (int i = 0; i < 64; i++) {
        float a = db1[i];
#pragma unroll
        for (int k = 0; k < 5; k++) a += dw1[k * 64 + i] * in5[k];
        a = fmaxf(a, 0.f);
#pragma unroll
        for (int j = 0; j < 64; j++) h2[j] += a * dw2[i * 64 + j];
    }

    float h3[64];
#pragma unroll
    for (int j = 0; j < 64; j++) h3[j] = db3[j];

#pragma unroll 4
    for (int i = 0; i < 64; i++) {
        float r = fmaxf(h2[i], 0.f);
#pragma unroll
        for (int j = 0; j < 64; j++) h3[j] += r * dw3[i * 64 + j];
    }

    float o = db4[0];
#pragma unroll 8
    for (int j = 0; j < 64; j++) o += fmaxf(h3[j], 0.f) * dw4[j];
    out[n] = yp[n] + o;
}

extern "C" void kernel_launch(void* const* d_in, const int* in_sizes, int n_in,
                              void* d_out, int out_size, void* d_ws, size_t ws_size,
                              hipStream_t stream) {
    const float* X    = (const float*)d_in[0];
    const float* yp   = (const float*)d_in[1];
    const int*   edge = (const int*)d_in[2];   // harness: integer -> const int*
    const float *ew1 = (const float*)d_in[3],  *eb1 = (const float*)d_in[4];
    const float *ew2 = (const float*)d_in[5],  *eb2 = (const float*)d_in[6];
    const float *ew3 = (const float*)d_in[7],  *eb3 = (const float*)d_in[8];
    const float *nw1 = (const float*)d_in[9],  *nb1 = (const float*)d_in[10];
    const float *nw2 = (const float*)d_in[11], *nb2 = (const float*)d_in[12];
    const float *nw3 = (const float*)d_in[13], *nb3 = (const float*)d_in[14];
    const float *dw1 = (const float*)d_in[15], *db1 = (const float*)d_in[16];
    const float *dw2 = (const float*)d_in[17], *db2 = (const float*)d_in[18];
    const float *dw3 = (const float*)d_in[19], *db3 = (const float*)d_in[20];
    const float *dw4 = (const float*)d_in[21], *db4 = (const float*)d_in[22];
    float* out = (float*)d_out;

    char* p = (char*)d_ws;
    auto carve = [&](size_t bytes) {
        char* r = p;
        p += (bytes + 255) & ~(size_t)255;
        return r;
    };
    int2*   sd   = (int2*)  carve(sizeof(int2)   * N_EDGES);
    float4* dnrm = (float4*)carve(sizeof(float4) * N_EDGES);
    float4* ea   = (float4*)carve(sizeof(float4) * N_EDGES);
    float4* px4  = (float4*)carve(sizeof(float4) * N_NODES);
    float*  f    = (float*) carve(sizeof(float)  * N_NODES);
    float*  cnt  = (float*) carve(sizeof(float)  * N_NODES);
    float*  aggr = (float*) carve(sizeof(float)  * 3 * N_NODES);

    const int nb_n = (N_NODES + 255) / 256;
    const int nb_e = (N_EDGES + 255) / 256;

    hipMemsetAsync(cnt, 0, sizeof(float) * N_NODES, stream);
    k_node_init<<<nb_n, 256, 0, stream>>>(X, yp, px4, f);
    k_edge_init<<<nb_e, 256, 0, stream>>>(edge, px4, yp, sd, dnrm, ea, cnt);

    for (int it = 0; it < 3; ++it) {
        hipMemsetAsync(aggr, 0, sizeof(float) * 3 * N_NODES, stream);
        k_edge_mlp<<<nb_e, 256, 0, stream>>>(sd, dnrm, ea, f,
                                             ew1, eb1, ew2, eb2, ew3, eb3, aggr);
        k_node_mlp<<<nb_n, 256, 0, stream>>>(px4, f, aggr, cnt,
                                             nw1, nb1, nw2, nb2, nw3, nb3);
    }
    k_decoder<<<nb_n, 256, 0, stream>>>(px4, f, yp,
                                        dw1, db1, dw2, db2, dw3, db3, dw4, db4, out);
}